// Round 4
// baseline (56527.618 us; speedup 1.0000x reference)
//
#include <hip/hip_runtime.h>
#include <cstdint>

#define TSTEPS 8192
#define FIN 256
#define HD 1024
#define ED 512
#define W1 128     // layer-1 compute wgs (4 waves, 2 rows/wave, lane-parity row split)
#define W2 64      // layer-2 compute wgs
#define NREL 16    // relay candidate wgs per kind (h1 / h2)
#define AG __HIP_MEMORY_SCOPE_AGENT
#define STALE_MAX 8192

typedef unsigned long long u64;
typedef unsigned int u32;
typedef u32 u32x4 __attribute__((ext_vector_type(4)));

// ---------------- ws layout ----------------
// master (coherence point, sc0 sc1 traffic):
//   u64 mp1[8][HD]  @ byte 0       (64 KB)   (tag lo-dword, value hi-dword)
//   u64 mp2[8][ED]  @ byte 65536   (32 KB)
//   u32 cons2[64]   @ u32 24576    L2 wg staged-h1 progress (ring WAR guard)
//   u32 claim1[8]   @ u32 24640    h1-relay per-XCD claim slots
//   u32 claim2[8]   @ u32 24648    h2-relay per-XCD claim slots
// per-XCD local copies (written by relays with plain stores -> dirty in that
// XCD's L2; read by same-XCD consumers with sc0-only loads -> L2 hits):
//   at byte 131072 + xcc*131072:
//     u64 lp1[8][HD] (+0, 64 KB); u64 lp2[8][ED] (+65536, 32 KB); u32 lmin (+98304)
#define CONS2_U32  24576
#define CLAIM1_U32 24640
#define CLAIM2_U32 24648
#define LOCAL_BYTE 131072
#define XSTRIDE    131072
#define LP2_BYTE   65536
#define LMIN_BYTE  98304

__global__ void init_ctrs(u32* ws32) {
  int i = threadIdx.x;
  if (i < 80) ws32[CONS2_U32 + i] = 0xFFFFFFFFu;          // cons2, claim1, claim2 = -1
  if (i >= 80 && i < 88)                                  // per-XCD lmin = -1
    *(u32*)((char*)ws32 + LOCAL_BYTE + (size_t)(i - 80) * XSTRIDE + LMIN_BYTE) = 0xFFFFFFFFu;
}

__device__ __forceinline__ float sigf(float z) { return 1.0f / (1.0f + expf(-z)); }
__device__ __forceinline__ float uaf(u32 v) { return __uint_as_float(v); }

#define TAGOK8(want,q0,q1,q2,q3,q4,q5,q6,q7)                                   \
  ((q0.x==want)&(q0.z==want)&(q1.x==want)&(q1.z==want)&                        \
   (q2.x==want)&(q2.z==want)&(q3.x==want)&(q3.z==want)&                        \
   (q4.x==want)&(q4.z==want)&(q5.x==want)&(q5.z==want)&                        \
   (q6.x==want)&(q6.z==want)&(q7.x==want)&(q7.z==want))

// 8x dwordx4 (16 pairs) + 1 guard dword, cache flags F ("sc0" = local L2 poll,
// "sc0 sc1" = master/MALL poll), single vmcnt wait.
#define LOAD8P(F, pb, cp, q0,q1,q2,q3,q4,q5,q6,q7, cv)                         \
  asm volatile(                                                                \
    "global_load_dwordx4 %0, %9, off " F "\n\t"                                \
    "global_load_dwordx4 %1, %9, off offset:16 " F "\n\t"                      \
    "global_load_dwordx4 %2, %9, off offset:32 " F "\n\t"                      \
    "global_load_dwordx4 %3, %9, off offset:48 " F "\n\t"                      \
    "global_load_dwordx4 %4, %9, off offset:64 " F "\n\t"                      \
    "global_load_dwordx4 %5, %9, off offset:80 " F "\n\t"                      \
    "global_load_dwordx4 %6, %9, off offset:96 " F "\n\t"                      \
    "global_load_dwordx4 %7, %9, off offset:112 " F "\n\t"                     \
    "global_load_dword %8, %10, off " F "\n\t"                                 \
    "s_waitcnt vmcnt(0)"                                                       \
    : "=&v"(q0),"=&v"(q1),"=&v"(q2),"=&v"(q3),                                 \
      "=&v"(q4),"=&v"(q5),"=&v"(q6),"=&v"(q7),"=&v"(cv)                        \
    : "v"(pb), "v"(cp) : "memory")

#define LOAD4P(F, pb, q0,q1,q2,q3)                                             \
  asm volatile(                                                                \
    "global_load_dwordx4 %0, %4, off " F "\n\t"                                \
    "global_load_dwordx4 %1, %4, off offset:16 " F "\n\t"                      \
    "global_load_dwordx4 %2, %4, off offset:32 " F "\n\t"                      \
    "global_load_dwordx4 %3, %4, off offset:48 " F "\n\t"                      \
    "s_waitcnt vmcnt(0)"                                                       \
    : "=&v"(q0),"=&v"(q1),"=&v"(q2),"=&v"(q3)                                  \
    : "v"(pb) : "memory")

// Grid 224 wgs x 256 thr, __launch_bounds__(256,2) caps VGPR<=256 so even
// pathological 2-wg/CU packing keeps everything co-resident (no deadlock).
//  [0,128)   L1 compute   [128,192) L2 compute
//  [192,208) h1-relay candidates   [208,224) h2-relay candidates
__global__ void __launch_bounds__(256, 2) lstm2_fused(
    const float* __restrict__ x,
    const float* __restrict__ w_ih1, const float* __restrict__ w_hh1,
    const float* __restrict__ b_ih1, const float* __restrict__ b_hh1,
    const float* __restrict__ w_ih2, const float* __restrict__ w_hh2,
    const float* __restrict__ b_ih2, const float* __restrict__ b_hh2,
    float* __restrict__ out, u32* __restrict__ ws32)
{
  u64* mp1 = (u64*)ws32;
  u64* mp2 = mp1 + 8 * HD;
  u32* cons2 = ws32 + CONS2_U32;

  const int bid  = blockIdx.x;
  const int tid  = threadIdx.x;
  const int wave = tid >> 6;
  const int lane = tid & 63;

  int xcc;
  asm volatile("s_getreg_b32 %0, hwreg(HW_REG_XCC_ID)" : "=s"(xcc));  // [m09]
  xcc &= 7;
  char* lbase = (char*)ws32 + LOCAL_BYTE + (size_t)xcc * XSTRIDE;
  u64* lp1  = (u64*)lbase;
  u64* lp2  = (u64*)(lbase + LP2_BYTE);
  u32* lmin = (u32*)(lbase + LMIN_BYTE);

  __shared__ float4 hsl[2 * 256];   // h1 stage, double-buffered, XOR-swizzled slots
  __shared__ float4 h2l[2 * 128];   // h2 stage, double-buffered
  __shared__ int sClaim;

  if (bid >= W1 + W2) {
    // =========================== relays ===========================
    const int kind = (bid - W1 - W2) < NREL ? 0 : 1;   // 0: h1, 1: h2
    if (tid == 0) {
      u32 exp = 0xFFFFFFFFu;
      bool win = __hip_atomic_compare_exchange_strong(
          ws32 + (kind ? CLAIM2_U32 : CLAIM1_U32) + xcc, &exp, (u32)bid,
          __ATOMIC_RELAXED, __ATOMIC_RELAXED, AG);
      sClaim = win ? 1 : 0;
    }
    __syncthreads();
    if (!sClaim) return;              // one relay of each kind per XCD survives

    if (kind == 0) {
      // h1 relay: 4 waves x 256 pairs (4/lane); per-wave independent loops.
      const int base = wave * 256 + lane * 4;
      for (int t = 0; t < TSTEPS; ++t) {
        const u64* src = mp1 + (size_t)(t & 7) * HD + base;
        u64* dst = lp1 + (size_t)(t & 7) * HD + base;
        const u32 want = (u32)t;
        u32x4 a, b;
        for (;;) {
          asm volatile(
            "global_load_dwordx4 %0, %2, off sc0 sc1\n\t"
            "global_load_dwordx4 %1, %2, off offset:16 sc0 sc1\n\t"
            "s_waitcnt vmcnt(0)"
            : "=&v"(a), "=&v"(b) : "v"(src) : "memory");
          bool ok = (a.x==want)&(a.z==want)&(b.x==want)&(b.z==want);
          if (__all(ok)) break;
        }
        *(u32x4*)dst = a;             // plain stores -> this XCD's L2 (dirty)
        *(u32x4*)(dst + 2) = b;
      }
    } else {
      // h2 relay: 4 waves x 128 pairs (2/lane); wave0 also mirrors min(cons2).
      const int base = wave * 128 + lane * 2;
      const u32* c2p = cons2 + lane;
      for (int s = 0; s < TSTEPS; ++s) {
        const u64* src = mp2 + (size_t)(s & 7) * ED + base;
        u64* dst = lp2 + (size_t)(s & 7) * ED + base;
        const u32 want = (u32)s;
        u32x4 a;
        for (;;) {
          if (wave == 0) {
            u32 cw;
            asm volatile(
              "global_load_dwordx4 %0, %2, off sc0 sc1\n\t"
              "global_load_dword %1, %3, off sc0 sc1\n\t"
              "s_waitcnt vmcnt(0)"
              : "=&v"(a), "=&v"(cw) : "v"(src), "v"(c2p) : "memory");
            int m = (int)cw;
#pragma unroll
            for (int d = 1; d < 64; d <<= 1) m = min(m, __shfl_xor(m, d, 64));
            if (lane == 0) *lmin = (u32)m;     // plain store -> local L2
          } else {
            asm volatile(
              "global_load_dwordx4 %0, %1, off sc0 sc1\n\t"
              "s_waitcnt vmcnt(0)"
              : "=&v"(a) : "v"(src) : "memory");
          }
          bool ok = (a.x==want)&(a.z==want);
          if (__all(ok)) break;
        }
        *(u32x4*)dst = a;
      }
    }
    return;
  }

  if (bid < W1) {
    // =========================== layer 1 ===========================
    const int half = lane & 1;
    const int kc   = lane >> 1;                     // k-chunk 0..31 (32 elems)
    const int ro   = bid * 8 + wave * 2 + half;     // owned h1 row
    const int kbase = kc * 32, xkbase = kc * 8;
    float whh[4][32], wih[4][8], bz[4];
#pragma unroll
    for (int g = 0; g < 4; ++g) {                   // PyTorch gate order i,f,g,o
      const float* wr = w_hh1 + ((size_t)(g * HD + ro)) * HD + kbase;
#pragma unroll
      for (int j = 0; j < 8; ++j) {
        float4 v = *(const float4*)(wr + j * 4);
        whh[g][j*4+0]=v.x; whh[g][j*4+1]=v.y; whh[g][j*4+2]=v.z; whh[g][j*4+3]=v.w;
      }
      const float* ur = w_ih1 + ((size_t)(g * HD + ro)) * FIN + xkbase;
      float4 a = *(const float4*)(ur), b = *(const float4*)(ur + 4);
      wih[g][0]=a.x; wih[g][1]=a.y; wih[g][2]=a.z; wih[g][3]=a.w;
      wih[g][4]=b.x; wih[g][5]=b.y; wih[g][6]=b.z; wih[g][7]=b.w;
      bz[g] = b_ih1[g * HD + ro] + b_hh1[g * HD + ro];
    }
    float cst = 0.f;
    bool useM = false;                              // sticky master-poll valve

    for (int t = 0; t < TSTEPS; ++t) {
      const float* xp = x + (size_t)t * FIN + xkbase;
      float4 xa = *(const float4*)(xp);
      float4 xb = *(const float4*)(xp + 4);
      const int sb = (t & 1) * 256;

      if (t == 0) {
        hsl[tid] = make_float4(0.f, 0.f, 0.f, 0.f);
      } else if (wave == 0) {
        const int slot = (t - 1) & 7;
        const u32 want = (u32)(t - 1);
        const int bp = t - 8;                       // ring WAR guard target
        const u64* lpb = lp1 + (size_t)slot * HD + lane * 16;
        const u64* mpb = mp1 + (size_t)slot * HD + lane * 16;
        const u32* mcp = cons2 + lane;
        u32x4 q0,q1,q2,q3,q4,q5,q6,q7; u32 cv;
        int stale = 0;
        for (;;) {
          if (!useM) {
            LOAD8P("sc0", lpb, lmin, q0,q1,q2,q3,q4,q5,q6,q7, cv);
            bool ok = TAGOK8(want,q0,q1,q2,q3,q4,q5,q6,q7) & ((int)cv >= bp);
            if (__all(ok)) break;
            if (++stale > STALE_MAX) useM = true;   // relay missing -> fallback
          } else {
            LOAD8P("sc0 sc1", mpb, mcp, q0,q1,q2,q3,q4,q5,q6,q7, cv);
            bool ok = TAGOK8(want,q0,q1,q2,q3,q4,q5,q6,q7) & ((int)cv >= bp);
            if (__all(ok)) break;
          }
        }
        const int f0 = lane * 4;
        hsl[sb + ((f0+0) ^ (((f0+0)>>3)&7))] = make_float4(uaf(q0.y),uaf(q0.w),uaf(q1.y),uaf(q1.w));
        hsl[sb + ((f0+1) ^ (((f0+1)>>3)&7))] = make_float4(uaf(q2.y),uaf(q2.w),uaf(q3.y),uaf(q3.w));
        hsl[sb + ((f0+2) ^ (((f0+2)>>3)&7))] = make_float4(uaf(q4.y),uaf(q4.w),uaf(q5.y),uaf(q5.w));
        hsl[sb + ((f0+3) ^ (((f0+3)>>3)&7))] = make_float4(uaf(q6.y),uaf(q6.w),uaf(q7.y),uaf(q7.w));
      }
      __syncthreads();

      float a0=0.f, a1=0.f, a2=0.f, a3=0.f;
#pragma unroll
      for (int j = 0; j < 8; ++j) {                 // stream LDS: low VGPR pressure
        const int f = kc * 8 + (j ^ (kc & 7));      // physical (swizzled) slot
        float4 v = hsl[sb + f];
        a0=fmaf(whh[0][j*4+0],v.x,a0); a0=fmaf(whh[0][j*4+1],v.y,a0);
        a0=fmaf(whh[0][j*4+2],v.z,a0); a0=fmaf(whh[0][j*4+3],v.w,a0);
        a1=fmaf(whh[1][j*4+0],v.x,a1); a1=fmaf(whh[1][j*4+1],v.y,a1);
        a1=fmaf(whh[1][j*4+2],v.z,a1); a1=fmaf(whh[1][j*4+3],v.w,a1);
        a2=fmaf(whh[2][j*4+0],v.x,a2); a2=fmaf(whh[2][j*4+1],v.y,a2);
        a2=fmaf(whh[2][j*4+2],v.z,a2); a2=fmaf(whh[2][j*4+3],v.w,a2);
        a3=fmaf(whh[3][j*4+0],v.x,a3); a3=fmaf(whh[3][j*4+1],v.y,a3);
        a3=fmaf(whh[3][j*4+2],v.z,a3); a3=fmaf(whh[3][j*4+3],v.w,a3);
      }
      float xvv[8] = {xa.x,xa.y,xa.z,xa.w,xb.x,xb.y,xb.z,xb.w};
#pragma unroll
      for (int j = 0; j < 8; ++j) {
        float xj = xvv[j];
        a0=fmaf(wih[0][j],xj,a0); a1=fmaf(wih[1][j],xj,a1);
        a2=fmaf(wih[2][j],xj,a2); a3=fmaf(wih[3][j],xj,a3);
      }
#pragma unroll
      for (int d = 2; d < 64; d <<= 1) {            // parity-preserving butterfly
        a0 += __shfl_xor(a0, d, 64);
        a1 += __shfl_xor(a1, d, 64);
        a2 += __shfl_xor(a2, d, 64);
        a3 += __shfl_xor(a3, d, 64);
      }
      float ig = sigf(a0 + bz[0]);
      float fg = sigf(a1 + bz[1]);
      float gg = tanhf(a2 + bz[2]);
      float og = sigf(a3 + bz[3]);
      cst = fg * cst + ig * gg;
      float h = og * tanhf(cst);

      if (lane < 2) {                               // fire-and-forget publication
        u64 pk = ((u64)__float_as_uint(h) << 32) | (u64)(u32)t;
        __hip_atomic_store(mp1 + (size_t)(t & 7) * HD + ro, pk, __ATOMIC_RELAXED, AG);
      }
    }
  } else {
    // =========================== layer 2 ===========================
    const int jwg  = bid - W1;
    const int half = lane & 1;
    const int kc   = lane >> 1;
    const int eo   = jwg * 8 + wave * 2 + half;     // owned h2 row
    const int kbase = kc * 32, k2base = kc * 16;
    float wA[4][32], wB[4][16], bz[4];
#pragma unroll
    for (int g = 0; g < 4; ++g) {
      const float* wr = w_ih2 + ((size_t)(g * ED + eo)) * HD + kbase;
#pragma unroll
      for (int j = 0; j < 8; ++j) {
        float4 v = *(const float4*)(wr + j * 4);
        wA[g][j*4+0]=v.x; wA[g][j*4+1]=v.y; wA[g][j*4+2]=v.z; wA[g][j*4+3]=v.w;
      }
      const float* wr2 = w_hh2 + ((size_t)(g * ED + eo)) * ED + k2base;
#pragma unroll
      for (int j = 0; j < 4; ++j) {
        float4 v = *(const float4*)(wr2 + j * 4);
        wB[g][j*4+0]=v.x; wB[g][j*4+1]=v.y; wB[g][j*4+2]=v.z; wB[g][j*4+3]=v.w;
      }
      bz[g] = b_ih2[g * ED + eo] + b_hh2[g * ED + eo];
    }
    float cst = 0.f;
    bool useM0 = false, useM1 = false;

    for (int s = 0; s < TSTEPS; ++s) {
      const int sb  = (s & 1) * 256;
      const int sb2 = (s & 1) * 128;

      if (wave == 0) {
        // detect+fetch h1[s] from local copy
        const int slot = s & 7;
        const u32 want = (u32)s;
        const u64* lpb = lp1 + (size_t)slot * HD + lane * 16;
        const u64* mpb = mp1 + (size_t)slot * HD + lane * 16;
        u32x4 q0,q1,q2,q3,q4,q5,q6,q7; u32 cv;
        int stale = 0;
        for (;;) {
          if (!useM0) {
            LOAD8P("sc0", lpb, lmin, q0,q1,q2,q3,q4,q5,q6,q7, cv);
            if (__all(TAGOK8(want,q0,q1,q2,q3,q4,q5,q6,q7))) break;
            if (++stale > STALE_MAX) useM0 = true;
          } else {
            LOAD8P("sc0 sc1", mpb, lmin, q0,q1,q2,q3,q4,q5,q6,q7, cv);
            if (__all(TAGOK8(want,q0,q1,q2,q3,q4,q5,q6,q7))) break;
          }
        }
        if (lane == 0)   // h1[s] safe in regs -> release ring slot for t=s+8
          __hip_atomic_store(cons2 + jwg, (u32)s, __ATOMIC_RELAXED, AG);
        const int f0 = lane * 4;
        hsl[sb + ((f0+0) ^ (((f0+0)>>3)&7))] = make_float4(uaf(q0.y),uaf(q0.w),uaf(q1.y),uaf(q1.w));
        hsl[sb + ((f0+1) ^ (((f0+1)>>3)&7))] = make_float4(uaf(q2.y),uaf(q2.w),uaf(q3.y),uaf(q3.w));
        hsl[sb + ((f0+2) ^ (((f0+2)>>3)&7))] = make_float4(uaf(q4.y),uaf(q4.w),uaf(q5.y),uaf(q5.w));
        hsl[sb + ((f0+3) ^ (((f0+3)>>3)&7))] = make_float4(uaf(q6.y),uaf(q6.w),uaf(q7.y),uaf(q7.w));
      } else if (wave == 1) {
        if (s == 0) {
          h2l[lane * 2] = make_float4(0.f,0.f,0.f,0.f);
          h2l[lane * 2 + 1] = make_float4(0.f,0.f,0.f,0.f);
        } else {
          const int slot = (s - 1) & 7;
          const u32 want = (u32)(s - 1);
          const u64* lpb = lp2 + (size_t)slot * ED + lane * 8;
          const u64* mpb = mp2 + (size_t)slot * ED + lane * 8;
          u32x4 q0,q1,q2,q3;
          int stale = 0;
          for (;;) {
            if (!useM1) {
              LOAD4P("sc0", lpb, q0,q1,q2,q3);
              bool ok = (q0.x==want)&(q0.z==want)&(q1.x==want)&(q1.z==want)
                      & (q2.x==want)&(q2.z==want)&(q3.x==want)&(q3.z==want);
              if (__all(ok)) break;
              if (++stale > STALE_MAX) useM1 = true;
            } else {
              LOAD4P("sc0 sc1", mpb, q0,q1,q2,q3);
              bool ok = (q0.x==want)&(q0.z==want)&(q1.x==want)&(q1.z==want)
                      & (q2.x==want)&(q2.z==want)&(q3.x==want)&(q3.z==want);
              if (__all(ok)) break;
            }
          }
          const int f0 = lane * 2;
          h2l[sb2 + ((f0+0) ^ (((f0+0)>>3)&7))] = make_float4(uaf(q0.y),uaf(q0.w),uaf(q1.y),uaf(q1.w));
          h2l[sb2 + ((f0+1) ^ (((f0+1)>>3)&7))] = make_float4(uaf(q2.y),uaf(q2.w),uaf(q3.y),uaf(q3.w));
        }
      }
      __syncthreads();

      float a0=0.f, a1=0.f, a2=0.f, a3=0.f;
#pragma unroll
      for (int j = 0; j < 8; ++j) {
        const int f = kc * 8 + (j ^ (kc & 7));
        float4 v = hsl[sb + f];
        a0=fmaf(wA[0][j*4+0],v.x,a0); a0=fmaf(wA[0][j*4+1],v.y,a0);
        a0=fmaf(wA[0][j*4+2],v.z,a0); a0=fmaf(wA[0][j*4+3],v.w,a0);
        a1=fmaf(wA[1][j*4+0],v.x,a1); a1=fmaf(wA[1][j*4+1],v.y,a1);
        a1=fmaf(wA[1][j*4+2],v.z,a1); a1=fmaf(wA[1][j*4+3],v.w,a1);
        a2=fmaf(wA[2][j*4+0],v.x,a2); a2=fmaf(wA[2][j*4+1],v.y,a2);
        a2=fmaf(wA[2][j*4+2],v.z,a2); a2=fmaf(wA[2][j*4+3],v.w,a2);
        a3=fmaf(wA[3][j*4+0],v.x,a3); a3=fmaf(wA[3][j*4+1],v.y,a3);
        a3=fmaf(wA[3][j*4+2],v.z,a3); a3=fmaf(wA[3][j*4+3],v.w,a3);
      }
#pragma unroll
      for (int j = 0; j < 4; ++j) {
        int L = kc * 4 + j;
        const int f = L ^ ((L >> 3) & 7);
        float4 v = h2l[sb2 + f];
        a0=fmaf(wB[0][j*4+0],v.x,a0); a0=fmaf(wB[0][j*4+1],v.y,a0);
        a0=fmaf(wB[0][j*4+2],v.z,a0); a0=fmaf(wB[0][j*4+3],v.w,a0);
        a1=fmaf(wB[1][j*4+0],v.x,a1); a1=fmaf(wB[1][j*4+1],v.y,a1);
        a1=fmaf(wB[1][j*4+2],v.z,a1); a1=fmaf(wB[1][j*4+3],v.w,a1);
        a2=fmaf(wB[2][j*4+0],v.x,a2); a2=fmaf(wB[2][j*4+1],v.y,a2);
        a2=fmaf(wB[2][j*4+2],v.z,a2); a2=fmaf(wB[2][j*4+3],v.w,a2);
        a3=fmaf(wB[3][j*4+0],v.x,a3); a3=fmaf(wB[3][j*4+1],v.y,a3);
        a3=fmaf(wB[3][j*4+2],v.z,a3); a3=fmaf(wB[3][j*4+3],v.w,a3);
      }
#pragma unroll
      for (int d = 2; d < 64; d <<= 1) {
        a0 += __shfl_xor(a0, d, 64);
        a1 += __shfl_xor(a1, d, 64);
        a2 += __shfl_xor(a2, d, 64);
        a3 += __shfl_xor(a3, d, 64);
      }
      float ig = sigf(a0 + bz[0]);
      float fg = sigf(a1 + bz[1]);
      float gg = tanhf(a2 + bz[2]);
      float og = sigf(a3 + bz[3]);
      cst = fg * cst + ig * gg;
      float h = og * tanhf(cst);

      if (lane < 2) {
        u64 pk = ((u64)__float_as_uint(h) << 32) | (u64)(u32)s;
        __hip_atomic_store(mp2 + (size_t)(s & 7) * ED + eo, pk, __ATOMIC_RELAXED, AG);
        if (s == TSTEPS - 1) out[eo] = h;
      }
    }
  }
}

extern "C" void kernel_launch(void* const* d_in, const int* in_sizes, int n_in,
                              void* d_out, int out_size, void* d_ws, size_t ws_size,
                              hipStream_t stream) {
  const float* x    = (const float*)d_in[0];
  const float* wih1 = (const float*)d_in[1];
  const float* whh1 = (const float*)d_in[2];
  const float* bih1 = (const float*)d_in[3];
  const float* bhh1 = (const float*)d_in[4];
  const float* wih2 = (const float*)d_in[5];
  const float* whh2 = (const float*)d_in[6];
  const float* bih2 = (const float*)d_in[7];
  const float* bhh2 = (const float*)d_in[8];
  float* out = (float*)d_out;
  u32* ws    = (u32*)d_ws;

  hipLaunchKernelGGL(init_ctrs, dim3(1), dim3(128), 0, stream, ws);
  hipLaunchKernelGGL(lstm2_fused, dim3(W1 + W2 + 2 * NREL), dim3(256), 0, stream,
                     x, wih1, whh1, bih1, bhh1, wih2, whh2, bih2, bhh2, out, ws);
}